// Round 3
// baseline (3517.571 us; speedup 1.0000x reference)
//
#include <hip/hip_runtime.h>

// Problem constants (match reference setup_inputs / module hyperparams)
#define BATCH 4
#define HGT   720
#define WID   1280
#define HW    (HGT * WID)           // 921600
#define NPIX  (BATCH * HW)          // 3686400
#define INV2S2 0.22222222222222222f // 1/(2*1.5^2)
#define INV_LAMBDA_E (255.0f / 30.0f)
#define THRESH 1e-6f
#define EPSV   1e-6f

// Splat tiling (gather formulation)
#define TILE   32
#define MARGIN 6          // covers all taps of sources with |u|,|v| < CUT (CUT+2 < 7)
#define EXT    (TILE + 2 * MARGIN)   // 44
#define EXTC   (EXT * EXT)           // 1936 source pixels per block
#define TC     (TILE * TILE)         // 1024 output cells
#define CUT    4.9f       // outlier threshold; P(|N(0,1)|>=4.9) ~ 1e-6

// ---------------------------------------------------------------------------
// Kernel 1: photometric error = mean_c |i1 - warp(i2, flow)|   -> err [N]
// ---------------------------------------------------------------------------
__global__ __launch_bounds__(256) void err_kernel(
    const float* __restrict__ i1, const float* __restrict__ i2,
    const float* __restrict__ flow, float* __restrict__ err) {
  int n = blockIdx.x * blockDim.x + threadIdx.x;
  if (n >= NPIX) return;
  int b = n / HW;
  int r = n - b * HW;
  int y = r / WID;
  int x = r - y * WID;

  float u = flow[(b * 2 + 0) * HW + r];
  float v = flow[(b * 2 + 1) * HW + r];
  float gx = fminf(fmaxf((float)x + u, 0.0f), (float)(WID - 1));
  float gy = fminf(fmaxf((float)y + v, 0.0f), (float)(HGT - 1));
  float x0f = floorf(gx), y0f = floorf(gy);
  int x0 = (int)x0f, y0 = (int)y0f;
  int x1 = min(x0 + 1, WID - 1), y1 = min(y0 + 1, HGT - 1);
  float wx = gx - x0f, wy = gy - y0f;
  float w00 = (1.0f - wx) * (1.0f - wy);
  float w01 = wx * (1.0f - wy);
  float w10 = (1.0f - wx) * wy;
  float w11 = wx * wy;
  int i00 = y0 * WID + x0, i01 = y0 * WID + x1;
  int i10 = y1 * WID + x0, i11 = y1 * WID + x1;

  const float* i2b = i2 + (size_t)b * 3 * HW;
  const float* i1b = i1 + (size_t)b * 3 * HW;
  float s = 0.0f;
#pragma unroll
  for (int c = 0; c < 3; ++c) {
    const float* p = i2b + c * HW;
    float wv = p[i00] * w00 + p[i01] * w01 + p[i10] * w10 + p[i11] * w11;
    s += fabsf(i1b[c * HW + r] - wv);
  }
  err[n] = s * (1.0f / 3.0f);
}

// ---------------------------------------------------------------------------
// Kernel 2: 3x3 zero-padded box filter of err, then fw = exp(-(e/LE)^2)
// ---------------------------------------------------------------------------
__global__ __launch_bounds__(256) void fw_kernel(
    const float* __restrict__ err, float* __restrict__ fw) {
  int n = blockIdx.x * blockDim.x + threadIdx.x;
  if (n >= NPIX) return;
  int b = n / HW;
  int r = n - b * HW;
  int y = r / WID;
  int x = r - y * WID;
  const float* e = err + (size_t)b * HW;
  float s = 0.0f;
#pragma unroll
  for (int dy = -1; dy <= 1; ++dy) {
    int yy = y + dy;
    if (yy < 0 || yy >= HGT) continue;
#pragma unroll
    for (int dx = -1; dx <= 1; ++dx) {
      int xx = x + dx;
      if (xx < 0 || xx >= WID) continue;
      s += e[yy * WID + xx];
    }
  }
  s *= (1.0f / 9.0f);
  float t = s * INV_LAMBDA_E;
  fw[n] = expf(-t * t);   // LAMBDA_V == 1
}

// ---------------------------------------------------------------------------
// Kernel 3: GATHER-form gaussian splat. Block owns output tile 32x32 of one
// batch image; scans the 44x44 extended source region, accumulates taps that
// land inside its tile into LDS (5 planes), then flushes with PLAIN coalesced
// stores (each output cell has exactly one owner; no memset, no atomics).
// Sources with |u| or |v| >= CUT are skipped here (deterministic predicate)
// and handled by outlier_kernel afterwards.
// TAO_R truncation is provably dead (min g = exp(-8/4.5) = 0.169 > 0.05).
// ---------------------------------------------------------------------------
__global__ __launch_bounds__(256) void splat_gather_kernel(
    const float* __restrict__ flow, const float* __restrict__ img,
    const float* __restrict__ fw, float* __restrict__ p,
    float* __restrict__ pw, float* __restrict__ rw) {
  __shared__ float sm[5 * TC];   // 20 KB: p0,p1,p2,pw,rw planes
  for (int i = threadIdx.x; i < 5 * TC; i += 256) sm[i] = 0.0f;
  __syncthreads();

  const int b = blockIdx.z;
  const int tx0 = blockIdx.x * TILE;
  const int ty0 = blockIdx.y * TILE;
  const int ex0 = tx0 - MARGIN;
  const int ey0 = ty0 - MARGIN;
  const float* fu  = flow + (size_t)(b * 2 + 0) * HW;
  const float* fv  = flow + (size_t)(b * 2 + 1) * HW;
  const float* ib  = img + (size_t)b * 3 * HW;
  const float* fwb = fw + (size_t)b * HW;

#pragma unroll
  for (int it = 0; it < (EXTC + 255) / 256; ++it) {
    int idx = threadIdx.x + it * 256;
    if (idx >= EXTC) continue;
    int ly = idx / EXT, lx = idx - ly * EXT;
    int sx = ex0 + lx, sy = ey0 + ly;
    if (sx < 0 || sx >= WID || sy < 0 || sy >= HGT) continue;
    int r = sy * WID + sx;
    float u = fu[r], v = fv[r];
    if (!(fabsf(u) < CUT && fabsf(v) < CUT)) continue;  // outlier pass handles

    float txf = (float)sx + u, tyf = (float)sy + v;
    float fx = floorf(txf), fy = floorf(tyf);
    int bx = (int)fx - 1 - tx0;   // tap cx = bx + dx, dx in [0,4)
    int by = (int)fy - 1 - ty0;
    // quick reject: tap window entirely outside tile
    if (bx <= -4 || bx >= TILE || by <= -4 || by >= TILE) continue;
    float fracx = txf - fx, fracy = tyf - fy;

    float gxv[4], gyv[4];
#pragma unroll
    for (int d = 0; d < 4; ++d) {
      float ddx = fracx - (float)(d - 1);
      gxv[d] = __expf(-ddx * ddx * INV2S2);
      float ddy = fracy - (float)(d - 1);
      gyv[d] = __expf(-ddy * ddy * INV2S2);
    }

    float fwv = fwb[r];
    float s0 = ib[0 * HW + r] * fwv;
    float s1 = ib[1 * HW + r] * fwv;
    float s2 = ib[2 * HW + r] * fwv;

#pragma unroll
    for (int dy = 0; dy < 4; ++dy) {
      int cy = by + dy;
      if (cy < 0 || cy >= TILE) continue;
      float gy = gyv[dy];
      int rowb = cy * TILE;
#pragma unroll
      for (int dx = 0; dx < 4; ++dx) {
        int cx = bx + dx;
        if (cx < 0 || cx >= TILE) continue;
        float g = gxv[dx] * gy;
        int cell = rowb + cx;
        unsafeAtomicAdd(&sm[0 * TC + cell], s0 * g);
        unsafeAtomicAdd(&sm[1 * TC + cell], s1 * g);
        unsafeAtomicAdd(&sm[2 * TC + cell], s2 * g);
        unsafeAtomicAdd(&sm[3 * TC + cell], fwv * g);
        unsafeAtomicAdd(&sm[4 * TC + cell], g);
      }
    }
  }
  __syncthreads();

  // flush: plain coalesced stores — this block is the sole owner of its tile
  const int base = b * HW;
#pragma unroll
  for (int c = threadIdx.x; c < TC; c += 256) {
    int cy = c >> 5, cx = c & 31;
    int gy = ty0 + cy;
    if (gy >= HGT) continue;        // bottom tile row is partial (720 = 22.5*32)
    int gi = base + gy * WID + tx0 + cx;
    p[gi]            = sm[0 * TC + c];
    p[NPIX + gi]     = sm[1 * TC + c];
    p[2 * NPIX + gi] = sm[2 * TC + c];
    pw[gi]           = sm[3 * TC + c];
    rw[gi]           = sm[4 * TC + c];
  }
}

// ---------------------------------------------------------------------------
// Kernel 3b: outlier splat — handles the ~4 pixels/frame with |flow| >= CUT
// via direct global atomics. Runs AFTER splat_gather (owner stores done).
// ---------------------------------------------------------------------------
__global__ __launch_bounds__(256) void outlier_kernel(
    const float* __restrict__ flow, const float* __restrict__ img,
    const float* __restrict__ fw, float* __restrict__ p,
    float* __restrict__ pw, float* __restrict__ rw) {
  int n = blockIdx.x * blockDim.x + threadIdx.x;
  if (n >= NPIX) return;
  int b = n / HW;
  int r = n - b * HW;
  float u = flow[(b * 2 + 0) * HW + r];
  float v = flow[(b * 2 + 1) * HW + r];
  if (fabsf(u) < CUT && fabsf(v) < CUT) return;  // complementary to gather

  int y = r / WID;
  int x = r - y * WID;
  float txf = (float)x + u, tyf = (float)y + v;
  float fx = floorf(txf), fy = floorf(tyf);
  int ixb = (int)fx, iyb = (int)fy;
  float fracx = txf - fx, fracy = tyf - fy;

  float gxv[4], gyv[4];
#pragma unroll
  for (int d = 0; d < 4; ++d) {
    float ddx = fracx - (float)(d - 1);
    gxv[d] = __expf(-ddx * ddx * INV2S2);
    float ddy = fracy - (float)(d - 1);
    gyv[d] = __expf(-ddy * ddy * INV2S2);
  }

  float fwv = fw[n];
  const float* ib = img + (size_t)b * 3 * HW;
  float s0 = ib[0 * HW + r] * fwv;
  float s1 = ib[1 * HW + r] * fwv;
  float s2 = ib[2 * HW + r] * fwv;

  int base = b * HW;
  for (int dy = 0; dy < 4; ++dy) {
    int iy = iyb + dy - 1;
    if (iy < 0 || iy >= HGT) continue;
    float gy = gyv[dy];
    for (int dx = 0; dx < 4; ++dx) {
      int ix = ixb + dx - 1;
      if (ix < 0 || ix >= WID) continue;
      float g = gxv[dx] * gy;
      int gi = base + iy * WID + ix;
      atomicAdd(p + gi, s0 * g);
      atomicAdd(p + NPIX + gi, s1 * g);
      atomicAdd(p + 2 * NPIX + gi, s2 * g);
      atomicAdd(pw + gi, fwv * g);
      atomicAdd(rw + gi, g);
    }
  }
}

// ---------------------------------------------------------------------------
// Kernel 4a: branch-1 accumulate: out = i1*w1 (write), den = w1 (write)
// ---------------------------------------------------------------------------
__global__ __launch_bounds__(256) void acc1_kernel(
    const float* __restrict__ p, const float* __restrict__ pw,
    const float* __restrict__ rw, float* __restrict__ out,
    float* __restrict__ den) {
  int n = blockIdx.x * blockDim.x + threadIdx.x;
  if (n >= NPIX) return;
  int b = n / HW;
  int r = n - b * HW;
  float pwv = pw[n], rwv = rw[n];
  float w = pwv / (rwv + THRESH);
  den[n] = w;
  float scale = w / (pwv + THRESH);
  int ob = b * 3 * HW + r;
  out[ob + 0 * HW] = p[n] * scale;
  out[ob + 1 * HW] = p[NPIX + n] * scale;
  out[ob + 2 * HW] = p[2 * NPIX + n] * scale;
}

// ---------------------------------------------------------------------------
// Kernel 4b: branch-2 accumulate + final blend:
//   out = (out + i2*w2) / (den + w2 + EPS)
// ---------------------------------------------------------------------------
__global__ __launch_bounds__(256) void acc2_kernel(
    const float* __restrict__ p, const float* __restrict__ pw,
    const float* __restrict__ rw, const float* __restrict__ den,
    float* __restrict__ out) {
  int n = blockIdx.x * blockDim.x + threadIdx.x;
  if (n >= NPIX) return;
  int b = n / HW;
  int r = n - b * HW;
  float pwv = pw[n], rwv = rw[n];
  float w = pwv / (rwv + THRESH);
  float scale = w / (pwv + THRESH);
  float d = den[n] + w + EPSV;
  float invd = 1.0f / d;
  int ob = b * 3 * HW + r;
  out[ob + 0 * HW] = (out[ob + 0 * HW] + p[n] * scale) * invd;
  out[ob + 1 * HW] = (out[ob + 1 * HW] + p[NPIX + n] * scale) * invd;
  out[ob + 2 * HW] = (out[ob + 2 * HW] + p[2 * NPIX + n] * scale) * invd;
}

// ---------------------------------------------------------------------------
// Launcher. Workspace layout (floats), 7N total = 103.2 MB:
//   [0, 3N)   p (3 planes); p[0] aliases err scratch (consumed before splat)
//   [3N, 4N)  pw   [4N, 5N)  rw   [5N, 6N)  fw   [6N, 7N)  den (w1)
// No memsets needed: gather stores fully initialize p/pw/rw before any read.
// ---------------------------------------------------------------------------
extern "C" void kernel_launch(void* const* d_in, const int* in_sizes, int n_in,
                              void* d_out, int out_size, void* d_ws,
                              size_t ws_size, hipStream_t stream) {
  const float* input1 = (const float*)d_in[0];
  const float* input2 = (const float*)d_in[1];
  const float* flow3  = (const float*)d_in[2];
  const float* flow4  = (const float*)d_in[3];
  float* out = (float*)d_out;

  float* ws  = (float*)d_ws;
  float* p   = ws;
  float* err = ws;
  float* pw  = ws + (size_t)3 * NPIX;
  float* rw  = ws + (size_t)4 * NPIX;
  float* fw  = ws + (size_t)5 * NPIX;
  float* den = ws + (size_t)6 * NPIX;

  const int threads = 256;
  const int blocks = (NPIX + threads - 1) / threads;
  dim3 sgrid(WID / TILE, (HGT + TILE - 1) / TILE, BATCH);  // 40 x 23 x 4

  // ---- branch 1: warp input2 by flow3, compare to input1, splat input1 ----
  err_kernel<<<blocks, threads, 0, stream>>>(input1, input2, flow3, err);
  fw_kernel<<<blocks, threads, 0, stream>>>(err, fw);
  splat_gather_kernel<<<sgrid, threads, 0, stream>>>(flow3, input1, fw, p, pw, rw);
  outlier_kernel<<<blocks, threads, 0, stream>>>(flow3, input1, fw, p, pw, rw);
  acc1_kernel<<<blocks, threads, 0, stream>>>(p, pw, rw, out, den);

  // ---- branch 2: warp input1 by flow4, compare to input2, splat input2 ----
  err_kernel<<<blocks, threads, 0, stream>>>(input2, input1, flow4, err);
  fw_kernel<<<blocks, threads, 0, stream>>>(err, fw);
  splat_gather_kernel<<<sgrid, threads, 0, stream>>>(flow4, input2, fw, p, pw, rw);
  outlier_kernel<<<blocks, threads, 0, stream>>>(flow4, input2, fw, p, pw, rw);
  acc2_kernel<<<blocks, threads, 0, stream>>>(p, pw, rw, den, out);
}

// Round 4
// 782.461 us; speedup vs baseline: 4.4955x; 4.4955x over previous
//
#include <hip/hip_runtime.h>

// Problem constants (match reference setup_inputs / module hyperparams)
#define BATCH 4
#define HGT   720
#define WID   1280
#define HW    (HGT * WID)           // 921600
#define NPIX  (BATCH * HW)          // 3686400
#define INV2S2 0.22222222222222222f // 1/(2*1.5^2)
#define INV_LAMBDA_E (255.0f / 30.0f)
#define THRESH 1e-6f
#define EPSV   1e-6f

// Gather-splat tiling: each lane owns one output pixel of a 16x16 tile and
// scans the 28x28 extended source region (margin 6 covers every tap of a
// source with |u|,|v| < CUT, since |tap - src| < CUT + 2 < 7).
#define GT   16
#define GM   6
#define GE   (GT + 2 * GM)   // 28
#define GEC  (GE * GE)       // 784 staged sources per block
#define CUT  4.9f            // outlier threshold; P(|N(0,1)|>=4.9) ~ 1e-6

// ---------------------------------------------------------------------------
// Kernel 1: photometric error = mean_c |i1 - warp(i2, flow)|   -> err [N]
// ---------------------------------------------------------------------------
__global__ __launch_bounds__(256) void err_kernel(
    const float* __restrict__ i1, const float* __restrict__ i2,
    const float* __restrict__ flow, float* __restrict__ err) {
  int n = blockIdx.x * blockDim.x + threadIdx.x;
  if (n >= NPIX) return;
  int b = n / HW;
  int r = n - b * HW;
  int y = r / WID;
  int x = r - y * WID;

  float u = flow[(b * 2 + 0) * HW + r];
  float v = flow[(b * 2 + 1) * HW + r];
  float gx = fminf(fmaxf((float)x + u, 0.0f), (float)(WID - 1));
  float gy = fminf(fmaxf((float)y + v, 0.0f), (float)(HGT - 1));
  float x0f = floorf(gx), y0f = floorf(gy);
  int x0 = (int)x0f, y0 = (int)y0f;
  int x1 = min(x0 + 1, WID - 1), y1 = min(y0 + 1, HGT - 1);
  float wx = gx - x0f, wy = gy - y0f;
  float w00 = (1.0f - wx) * (1.0f - wy);
  float w01 = wx * (1.0f - wy);
  float w10 = (1.0f - wx) * wy;
  float w11 = wx * wy;
  int i00 = y0 * WID + x0, i01 = y0 * WID + x1;
  int i10 = y1 * WID + x0, i11 = y1 * WID + x1;

  const float* i2b = i2 + (size_t)b * 3 * HW;
  const float* i1b = i1 + (size_t)b * 3 * HW;
  float s = 0.0f;
#pragma unroll
  for (int c = 0; c < 3; ++c) {
    const float* p = i2b + c * HW;
    float wv = p[i00] * w00 + p[i01] * w01 + p[i10] * w10 + p[i11] * w11;
    s += fabsf(i1b[c * HW + r] - wv);
  }
  err[n] = s * (1.0f / 3.0f);
}

// ---------------------------------------------------------------------------
// Kernel 2: 3x3 zero-padded box filter of err, then fw = exp(-(e/LE)^2)
// ---------------------------------------------------------------------------
__global__ __launch_bounds__(256) void fw_kernel(
    const float* __restrict__ err, float* __restrict__ fw) {
  int n = blockIdx.x * blockDim.x + threadIdx.x;
  if (n >= NPIX) return;
  int b = n / HW;
  int r = n - b * HW;
  int y = r / WID;
  int x = r - y * WID;
  const float* e = err + (size_t)b * HW;
  float s = 0.0f;
#pragma unroll
  for (int dy = -1; dy <= 1; ++dy) {
    int yy = y + dy;
    if (yy < 0 || yy >= HGT) continue;
#pragma unroll
    for (int dx = -1; dx <= 1; ++dx) {
      int xx = x + dx;
      if (xx < 0 || xx >= WID) continue;
      s += e[yy * WID + xx];
    }
  }
  s *= (1.0f / 9.0f);
  float t = s * INV_LAMBDA_E;
  fw[n] = expf(-t * t);   // LAMBDA_V == 1
}

// ---------------------------------------------------------------------------
// Kernel 3: register-gather gaussian splat — ZERO atomics.
// Lane owns output (X,Y). Stage 28x28 source region (uv + premultiplied
// vals) into LDS, then scan 13x13 candidate offsets accumulating in regs.
// Candidate predicate and weight replicate the reference bit-exactly:
//   tx = (float)sx + u  (Xf + (ox-6) is an exact integer float sum)
//   hit iff floor(tx) - X in [-2, 1]   (<=> X in tap window, dxi in [-1,2])
//   g = exp(-((tx-X)^2 + (ty-Y)^2) * INV2S2)   (subtractions exact)
// TAO_R truncation is dead (min in-window g = exp(-8/4.5) = 0.169 > 0.05).
// Outlier sources (|u| or |v| >= CUT) are staged as sentinel -> never hit;
// outlier_kernel adds them afterwards with global atomics (~4 px / frame).
// ---------------------------------------------------------------------------
__global__ __launch_bounds__(256) void splat_gather_kernel(
    const float* __restrict__ flow, const float* __restrict__ img,
    const float* __restrict__ fw, float* __restrict__ p,
    float* __restrict__ pw, float* __restrict__ rw) {
  __shared__ float2 suv[GEC];    // (u,v) or (1e9,1e9) sentinel
  __shared__ float4 sval[GEC];   // (i0*fw, i1*fw, i2*fw, fw)

  const int b = blockIdx.z;
  const int tx0 = blockIdx.x * GT;
  const int ty0 = blockIdx.y * GT;
  const int ex0 = tx0 - GM;
  const int ey0 = ty0 - GM;
  const float* fu  = flow + (size_t)(b * 2 + 0) * HW;
  const float* fv  = flow + (size_t)(b * 2 + 1) * HW;
  const float* ib  = img + (size_t)b * 3 * HW;
  const float* fwb = fw + (size_t)b * HW;

  // ---- stage sources ----
  for (int i = threadIdx.x; i < GEC; i += 256) {
    int ly = i / GE, lx = i - ly * GE;
    int sx = ex0 + lx, sy = ey0 + ly;
    float2 uv = make_float2(1e9f, 1e9f);
    float4 vl = make_float4(0.f, 0.f, 0.f, 0.f);
    if (sx >= 0 && sx < WID && sy >= 0 && sy < HGT) {
      int r = sy * WID + sx;
      float u = fu[r], v = fv[r];
      if (fabsf(u) < CUT && fabsf(v) < CUT) {   // complement of outlier_kernel
        uv = make_float2(u, v);
        float fwv = fwb[r];
        vl = make_float4(ib[r] * fwv, ib[HW + r] * fwv, ib[2 * HW + r] * fwv,
                         fwv);
      }
    }
    suv[i] = uv;
    sval[i] = vl;
  }
  __syncthreads();

  // ---- gather ----
  const int lx = threadIdx.x & 15;
  const int ly = threadIdx.x >> 4;
  const float Xf = (float)(tx0 + lx);
  const float Yf = (float)(ty0 + ly);

  float a0 = 0.f, a1 = 0.f, a2 = 0.f, apw = 0.f, arw = 0.f;

  for (int oy = 0; oy < 2 * GM + 1; ++oy) {
    const int rowb = (ly + oy) * GE + lx;
    const float oyf = (float)(oy - GM);
#pragma unroll
    for (int ox = 0; ox < 2 * GM + 1; ++ox) {
      float2 uv = suv[rowb + ox];
      float tx = (Xf + (float)(ox - GM)) + uv.x;  // == (float)sx + u exactly
      float ty = (Yf + oyf) + uv.y;
      float dxf = floorf(tx) - Xf;                // = -dxi, in [-2,1] iff hit
      float dyf = floorf(ty) - Yf;
      if (dxf >= -2.0f && dxf <= 1.0f && dyf >= -2.0f && dyf <= 1.0f) {
        float ddx = tx - Xf;                      // exact
        float ddy = ty - Yf;
        float g = __expf(-(ddx * ddx + ddy * ddy) * INV2S2);
        float4 vl = sval[rowb + ox];
        a0 += vl.x * g;
        a1 += vl.y * g;
        a2 += vl.z * g;
        apw += vl.w * g;
        arw += g;
      }
    }
  }

  // ---- plain coalesced stores: sole owner of this output pixel ----
  const int gi = b * HW + (ty0 + ly) * WID + tx0 + lx;
  p[gi]            = a0;
  p[NPIX + gi]     = a1;
  p[2 * NPIX + gi] = a2;
  pw[gi]           = apw;
  rw[gi]           = arw;
}

// ---------------------------------------------------------------------------
// Kernel 3b: outlier splat — handles the ~4 pixels/frame with |flow| >= CUT
// via direct global atomics. Runs AFTER splat_gather (owner stores done).
// ---------------------------------------------------------------------------
__global__ __launch_bounds__(256) void outlier_kernel(
    const float* __restrict__ flow, const float* __restrict__ img,
    const float* __restrict__ fw, float* __restrict__ p,
    float* __restrict__ pw, float* __restrict__ rw) {
  int n = blockIdx.x * blockDim.x + threadIdx.x;
  if (n >= NPIX) return;
  int b = n / HW;
  int r = n - b * HW;
  float u = flow[(b * 2 + 0) * HW + r];
  float v = flow[(b * 2 + 1) * HW + r];
  if (fabsf(u) < CUT && fabsf(v) < CUT) return;  // complementary to gather

  int y = r / WID;
  int x = r - y * WID;
  float txf = (float)x + u, tyf = (float)y + v;
  float fx = floorf(txf), fy = floorf(tyf);
  int ixb = (int)fx, iyb = (int)fy;
  float fracx = txf - fx, fracy = tyf - fy;

  float gxv[4], gyv[4];
#pragma unroll
  for (int d = 0; d < 4; ++d) {
    float ddx = fracx - (float)(d - 1);
    gxv[d] = __expf(-ddx * ddx * INV2S2);
    float ddy = fracy - (float)(d - 1);
    gyv[d] = __expf(-ddy * ddy * INV2S2);
  }

  float fwv = fw[n];
  const float* ib = img + (size_t)b * 3 * HW;
  float s0 = ib[0 * HW + r] * fwv;
  float s1 = ib[1 * HW + r] * fwv;
  float s2 = ib[2 * HW + r] * fwv;

  int base = b * HW;
  for (int dy = 0; dy < 4; ++dy) {
    int iy = iyb + dy - 1;
    if (iy < 0 || iy >= HGT) continue;
    float gy = gyv[dy];
    for (int dx = 0; dx < 4; ++dx) {
      int ix = ixb + dx - 1;
      if (ix < 0 || ix >= WID) continue;
      float g = gxv[dx] * gy;
      int gi = base + iy * WID + ix;
      atomicAdd(p + gi, s0 * g);
      atomicAdd(p + NPIX + gi, s1 * g);
      atomicAdd(p + 2 * NPIX + gi, s2 * g);
      atomicAdd(pw + gi, fwv * g);
      atomicAdd(rw + gi, g);
    }
  }
}

// ---------------------------------------------------------------------------
// Kernel 4a: branch-1 accumulate: out = i1*w1 (write), den = w1 (write)
// ---------------------------------------------------------------------------
__global__ __launch_bounds__(256) void acc1_kernel(
    const float* __restrict__ p, const float* __restrict__ pw,
    const float* __restrict__ rw, float* __restrict__ out,
    float* __restrict__ den) {
  int n = blockIdx.x * blockDim.x + threadIdx.x;
  if (n >= NPIX) return;
  int b = n / HW;
  int r = n - b * HW;
  float pwv = pw[n], rwv = rw[n];
  float w = pwv / (rwv + THRESH);
  den[n] = w;
  float scale = w / (pwv + THRESH);
  int ob = b * 3 * HW + r;
  out[ob + 0 * HW] = p[n] * scale;
  out[ob + 1 * HW] = p[NPIX + n] * scale;
  out[ob + 2 * HW] = p[2 * NPIX + n] * scale;
}

// ---------------------------------------------------------------------------
// Kernel 4b: branch-2 accumulate + final blend:
//   out = (out + i2*w2) / (den + w2 + EPS)
// ---------------------------------------------------------------------------
__global__ __launch_bounds__(256) void acc2_kernel(
    const float* __restrict__ p, const float* __restrict__ pw,
    const float* __restrict__ rw, const float* __restrict__ den,
    float* __restrict__ out) {
  int n = blockIdx.x * blockDim.x + threadIdx.x;
  if (n >= NPIX) return;
  int b = n / HW;
  int r = n - b * HW;
  float pwv = pw[n], rwv = rw[n];
  float w = pwv / (rwv + THRESH);
  float scale = w / (pwv + THRESH);
  float d = den[n] + w + EPSV;
  float invd = 1.0f / d;
  int ob = b * 3 * HW + r;
  out[ob + 0 * HW] = (out[ob + 0 * HW] + p[n] * scale) * invd;
  out[ob + 1 * HW] = (out[ob + 1 * HW] + p[NPIX + n] * scale) * invd;
  out[ob + 2 * HW] = (out[ob + 2 * HW] + p[2 * NPIX + n] * scale) * invd;
}

// ---------------------------------------------------------------------------
// Launcher. Workspace layout (floats), 7N total = 103.2 MB:
//   [0, 3N)   p (3 planes); p[0] aliases err scratch (consumed before splat)
//   [3N, 4N)  pw   [4N, 5N)  rw   [5N, 6N)  fw   [6N, 7N)  den (w1)
// No memsets: gather stores fully initialize p/pw/rw before any read.
// ---------------------------------------------------------------------------
extern "C" void kernel_launch(void* const* d_in, const int* in_sizes, int n_in,
                              void* d_out, int out_size, void* d_ws,
                              size_t ws_size, hipStream_t stream) {
  const float* input1 = (const float*)d_in[0];
  const float* input2 = (const float*)d_in[1];
  const float* flow3  = (const float*)d_in[2];
  const float* flow4  = (const float*)d_in[3];
  float* out = (float*)d_out;

  float* ws  = (float*)d_ws;
  float* p   = ws;
  float* err = ws;
  float* pw  = ws + (size_t)3 * NPIX;
  float* rw  = ws + (size_t)4 * NPIX;
  float* fw  = ws + (size_t)5 * NPIX;
  float* den = ws + (size_t)6 * NPIX;

  const int threads = 256;
  const int blocks = (NPIX + threads - 1) / threads;
  dim3 sgrid(WID / GT, HGT / GT, BATCH);  // 80 x 45 x 4, all tiles full

  // ---- branch 1: warp input2 by flow3, compare to input1, splat input1 ----
  err_kernel<<<blocks, threads, 0, stream>>>(input1, input2, flow3, err);
  fw_kernel<<<blocks, threads, 0, stream>>>(err, fw);
  splat_gather_kernel<<<sgrid, threads, 0, stream>>>(flow3, input1, fw, p, pw, rw);
  outlier_kernel<<<blocks, threads, 0, stream>>>(flow3, input1, fw, p, pw, rw);
  acc1_kernel<<<blocks, threads, 0, stream>>>(p, pw, rw, out, den);

  // ---- branch 2: warp input1 by flow4, compare to input2, splat input2 ----
  err_kernel<<<blocks, threads, 0, stream>>>(input2, input1, flow4, err);
  fw_kernel<<<blocks, threads, 0, stream>>>(err, fw);
  splat_gather_kernel<<<sgrid, threads, 0, stream>>>(flow4, input2, fw, p, pw, rw);
  outlier_kernel<<<blocks, threads, 0, stream>>>(flow4, input2, fw, p, pw, rw);
  acc2_kernel<<<blocks, threads, 0, stream>>>(p, pw, rw, den, out);
}